// Round 1
// 197.904 us; speedup vs baseline: 1.0326x; 1.0326x over previous
//
#include <hip/hip_runtime.h>

// RegionSeparatedAttention on MI355X — round 20: k_attn m-tile 128 via
// 8-wave blocks (staged-byte halving WITHOUT per-wave register growth).
//
// Theory: k_attn is bound by global_load_lds staged bytes (1 GB @ ~11.6
// TB/s ceiling = 88 us).  Previous m-tile-128 attempts doubled per-wave
// accumulators -> spills.  This variant keeps the per-wave footprint
// IDENTICAL (same 4 accs, mf[2][4]) and adds a second m-half as 4 more
// waves: block = 512 thr = (wj 2) x (jsw 2) x (mh 2), grid 256 = 8 br x
// 32 mt(128 rows).  Staged bytes halve to 512 MB -> predicted ~50 us.
//
// Global layouts in ws (per region br = b*4 + gi*2 + gj), ALL pre-swizzled:
//   Qp,Kp : bf16 [8][4096 n][64 c] pixel-major rows, seg' = seg ^ (n & 7)
//           (Q pre-scaled by 0.125*log2e)
//   Atl,Btl: bf16 [8][128 jtile][64 c][32 j], seg' = seg ^ ((c>>1) & 3)
//           (A gets *= Linv[j] in k_ascale)
//   OutP  : bf16 [8][4096 n][64 c] pixel-major, UNswizzled
//   Linv  : f32 [8][4096]   (1 / softmax row sum, from k_ascale)
//   Lpart : f32 [2 ms][8][4096] partial row sums (k_stats)

typedef __attribute__((ext_vector_type(8)))  short bf16x8;
typedef __attribute__((ext_vector_type(16))) float f32x16;

#define MFMA32(a, b, c) __builtin_amdgcn_mfma_f32_32x32x16_bf16(a, b, c, 0, 0, 0)

constexpr int REG_ELEMS = 4096 * 64;
constexpr size_t QP_OFF    = 0;
constexpr size_t KP_OFF    = 4u  << 20;
constexpr size_t ATL_OFF   = 8u  << 20;
constexpr size_t BTL_OFF   = 12u << 20;
constexpr size_t OUTP_OFF  = 16u << 20;
constexpr size_t LNV_OFF   = 20u << 20;                  // f32 [8][4096]
constexpr size_t LPART_OFF = (20u << 20) + (128u << 10); // f32 [2][8][4096]

constexpr float QSCALE = 0.18033688011112042f;  // 0.125 * log2(e)

__device__ __forceinline__ short f2bf(float f) {   // RNE
    union { float f; unsigned u; } v; v.f = f;
    unsigned r = v.u + 0x7fffu + ((v.u >> 16) & 1u);
    return (short)(r >> 16);
}
__device__ __forceinline__ float bf2f(short s) {
    union { unsigned u; float f; } v; v.u = ((unsigned)(unsigned short)s) << 16;
    return v.f;
}
__device__ __forceinline__ unsigned fbits(float f) {
    union { float f; unsigned u; } v; v.f = f; return v.u;
}
__device__ __forceinline__ unsigned pack_trunc(float e0, float e1) {
    return __builtin_amdgcn_perm(fbits(e1), fbits(e0), 0x07060302u);
}
__device__ __forceinline__ f32x16 zero16() {
    f32x16 z;
    #pragma unroll
    for (int i = 0; i < 16; ++i) z[i] = 0.f;
    return z;
}
__device__ __forceinline__ float fexp2(float x) {
#if __has_builtin(__builtin_amdgcn_exp2f)
    return __builtin_amdgcn_exp2f(x);
#else
    return exp2f(x);
#endif
}
__device__ __forceinline__ void permswap32(unsigned& a, unsigned& b, bool hi) {
#if __has_builtin(__builtin_amdgcn_permlane32_swap)
    auto r = __builtin_amdgcn_permlane32_swap(a, b, false, false);
    a = r[0]; b = r[1];
#elif __has_builtin(__builtin_amdgcn_permlane32_swap_b32)
    auto r = __builtin_amdgcn_permlane32_swap_b32(a, b, false, false);
    a = r[0]; b = r[1];
#else
    unsigned ax = (unsigned)__shfl_xor((int)a, 32);
    unsigned bx = (unsigned)__shfl_xor((int)b, 32);
    unsigned na = hi ? bx : a;
    unsigned nb = hi ? b  : ax;
    a = na; b = nb;
#endif
}

typedef __attribute__((address_space(1))) const unsigned char as1_t;
typedef __attribute__((address_space(3))) unsigned char as3_t;
__device__ __forceinline__ void stage16(const void* g, void* l) {
    __builtin_amdgcn_global_load_lds((as1_t*)g, (as3_t*)l, 16, 0, 0);
}

// ---------------------------------------------------------------- k_conv_in
// (round-8/13 green verbatim)
__global__ __launch_bounds__(256) void k_conv_in(
    const float* __restrict__ x,
    const float* __restrict__ Wq, const float* __restrict__ bq,
    const float* __restrict__ Wk, const float* __restrict__ bk,
    const float* __restrict__ Wa, const float* __restrict__ ba,
    const float* __restrict__ Wb, const float* __restrict__ bb,
    char* __restrict__ ws)
{
    const int tid  = threadIdx.x;
    const int blk  = blockIdx.x;
    const int wseg = blk & 1;
    const int h    = (blk >> 1) & 127;
    const int b    = blk >> 8;
    const int br   = b * 4 + (h >> 6) * 2 + wseg;
    const int n0   = (h & 63) * 64;

    __shared__ float xs[64][68];               // [c][px]
    __shared__ short trans[2][64][72];         // [mat][px][oc]

    const float* xp = x + ((size_t)b * 64 * 16384) + (size_t)h * 128 + wseg * 64;
    #pragma unroll
    for (int r = 0; r < 4; ++r) {
        int idx = r * 256 + tid;
        int c   = idx >> 4;
        int w4  = (idx & 15) << 2;
        *(float4*)&xs[c][w4] = *(const float4*)(xp + (size_t)c * 16384 + w4);
    }
    __syncthreads();

    const int lane = tid & 63;
    const int wid  = tid >> 6;
    const int col  = lane & 31;
    const int l5   = lane >> 5;
    const int pH   = wid & 1;                  // pixel half
    const int oH   = wid >> 1;                 // oc half
    const int px   = pH * 32 + col;
    const int oc   = oH * 32 + col;

    bf16x8 xhi[4], xlo[4];
    #pragma unroll
    for (int s = 0; s < 4; ++s) {
        union { bf16x8 v; short sh[8]; } uh, ul;
        #pragma unroll
        for (int e = 0; e < 8; ++e) {
            float xv = xs[s * 16 + l5 * 8 + e][px];
            short hh = f2bf(xv);
            uh.sh[e] = hh;
            ul.sh[e] = f2bf(xv - bf2f(hh));
        }
        xhi[s] = uh.v; xlo[s] = ul.v;
    }

    #pragma unroll
    for (int mat = 0; mat < 4; ++mat) {
        const float* Wsel = (mat == 0) ? Wq : (mat == 1) ? Wk : (mat == 2) ? Wa : Wb;
        const float* bsel = (mat == 0) ? bq : (mat == 1) ? bk : (mat == 2) ? ba : bb;

        bf16x8 whi[4], wlo[4];
        const float* wrow = Wsel + (size_t)oc * 64;
        #pragma unroll
        for (int s = 0; s < 4; ++s) {
            float4 f0 = *(const float4*)(wrow + s * 16 + l5 * 8);
            float4 f1 = *(const float4*)(wrow + s * 16 + l5 * 8 + 4);
            float wf[8] = { f0.x, f0.y, f0.z, f0.w, f1.x, f1.y, f1.z, f1.w };
            union { bf16x8 v; short sh[8]; } uh, ul;
            #pragma unroll
            for (int e = 0; e < 8; ++e) {
                short hh = f2bf(wf[e]);
                uh.sh[e] = hh;
                ul.sh[e] = f2bf(wf[e] - bf2f(hh));
            }
            whi[s] = uh.v; wlo[s] = ul.v;
        }

        f32x16 d = zero16();
        #pragma unroll
        for (int s = 0; s < 4; ++s) {
            d = MFMA32(xhi[s], whi[s], d);
            d = MFMA32(xhi[s], wlo[s], d);
            d = MFMA32(xlo[s], whi[s], d);
        }

        const float bias = bsel[oc];
        if (mat < 2) {
            const float sc = (mat == 0) ? QSCALE : 1.0f;
            #pragma unroll
            for (int r = 0; r < 16; ++r) {
                int pxl = pH * 32 + (r & 3) + 8 * (r >> 2) + 4 * l5;
                trans[mat][pxl][oc] = f2bf((d[r] + bias) * sc);
            }
        } else {
            short* base = (short*)(ws + (mat == 2 ? ATL_OFF : BTL_OFF))
                          + (size_t)br * REG_ELEMS;
            const int sw   = (oc >> 1) & 3;
            const int tile = (n0 >> 5) + pH;
            #pragma unroll
            for (int q = 0; q < 4; ++q) {
                short tmp4[4];
                #pragma unroll
                for (int rr = 0; rr < 4; ++rr) tmp4[rr] = f2bf(d[4 * q + rr] + bias);
                int segp = q ^ sw;
                short* p = base + (size_t)tile * 2048 + oc * 32 + segp * 8 + 4 * l5;
                *(uint2*)p = *(uint2*)tmp4;
            }
        }
    }
    __syncthreads();

    #pragma unroll
    for (int rep = 0; rep < 4; ++rep) {
        int idx  = rep * 256 + tid;
        int mat2 = idx >> 9;
        int row  = (idx >> 3) & 63;
        int seg  = idx & 7;
        short* dst = (short*)(ws + (mat2 ? KP_OFF : QP_OFF))
                     + (size_t)br * REG_ELEMS + (size_t)(n0 + row) * 64
                     + (seg ^ (row & 7)) * 8;
        *(uint4*)dst = *(uint4*)&trans[mat2][row][seg * 8];
    }
}

// ------------------------------------------------------------------ k_stats
// (r13 green m-split verbatim)
__global__ __launch_bounds__(256, 2) void k_stats(char* __restrict__ ws)
{
    const int tid  = threadIdx.x;
    const int br   = blockIdx.x & 7;
    const int nt   = (blockIdx.x >> 3) & 63;
    const int ms   = blockIdx.x >> 9;          // m-half
    const int lane = tid & 63;
    const int w    = tid >> 6;
    const int wn   = w & 1;
    const int wi   = w >> 1;
    const int col  = lane & 31;
    const int l5   = lane >> 5;

    const short* Qb  = (const short*)(ws + QP_OFF) + (size_t)br * REG_ELEMS;
    const char*  Kbb = ws + KP_OFF + (size_t)br * REG_ELEMS * 2
                       + (size_t)ms * 262144;  // 2048 rows * 128 B

    __shared__ __align__(16) char smem[16896];  // dbuf 16K | Lred 512

    const int nrow = nt * 64 + wn * 32 + col;
    bf16x8 afr[4];
    #pragma unroll
    for (int s = 0; s < 4; ++s)
        afr[s] = *(const bf16x8*)(Qb + (size_t)nrow * 64 + (((2*s+l5) ^ (col & 7)) * 8));

    float sm[16];
    #pragma unroll
    for (int r = 0; r < 16; ++r) sm[r] = 0.f;

    {   // stage slab 0 (64 m-rows = 8 KB; wave w covers 2 KB)
        const char* g = Kbb + (size_t)w * 2048 + lane * 16;
        char* l = smem + w * 2048;
        stage16(g, l); stage16(g + 1024, l + 1024);
    }

    #pragma unroll 2
    for (int slab = 0; slab < 32; ++slab) {
        __syncthreads();
        if (slab + 1 < 32) {
            const char* g = Kbb + (size_t)(slab + 1) * 8192 + w * 2048 + lane * 16;
            char* l = smem + ((slab + 1) & 1) * 8192 + w * 2048;
            stage16(g, l); stage16(g + 1024, l + 1024);
        }
        const short* Ks = (const short*)(smem + (slab & 1) * 8192);
        f32x16 d = zero16();
        #pragma unroll
        for (int s = 0; s < 4; ++s) {
            bf16x8 bf = *(const bf16x8*)(Ks + (wi * 32 + col) * 64
                                         + ((2*s+l5) ^ (col & 7)) * 8);
            d = MFMA32(afr[s], bf, d);
        }
        #pragma unroll
        for (int r = 0; r < 16; ++r) sm[r] += fexp2(d[r]);
    }

    #pragma unroll
    for (int off = 1; off < 32; off <<= 1)
        #pragma unroll
        for (int r = 0; r < 16; ++r) sm[r] += __shfl_xor(sm[r], off);

    __syncthreads();
    float* Lred = (float*)(smem + 16384);      // [4][32]
    if (col == 0) {
        #pragma unroll
        for (int r = 0; r < 16; ++r)
            Lred[w * 32 + ((r & 3) + 8 * (r >> 2) + 4 * l5)] = sm[r];
    }
    __syncthreads();
    if (tid < 64) {
        int wn2 = tid >> 5, nl = tid & 31;
        float L = Lred[wn2 * 32 + nl] + Lred[(wn2 + 2) * 32 + nl];
        ((float*)(ws + LPART_OFF))[(size_t)ms * 32768 + (size_t)br * 4096
                                   + nt * 64 + tid] = L;
    }
}

// ------------------------------------------------------------------ k_ascale
// (r13 green verbatim)
__global__ __launch_bounds__(256) void k_ascale(char* __restrict__ ws)
{
    const int tid = threadIdx.x;
    const int br  = blockIdx.x & 7;
    const int nt  = blockIdx.x >> 3;           // 0..63

    __shared__ float Larr[64];

    if (tid < 64) {
        const float* Lp = (const float*)(ws + LPART_OFF);
        const size_t idx = (size_t)br * 4096 + nt * 64 + tid;
        float li = 1.0f / (Lp[idx] + Lp[32768 + idx]);
        Larr[tid] = li;
        ((float*)(ws + LNV_OFF))[idx] = li;
    }
    __syncthreads();

    short* Ab = (short*)(ws + ATL_OFF) + (size_t)br * REG_ELEMS + (size_t)nt * 4096;
    #pragma unroll
    for (int rep = 0; rep < 2; ++rep) {
        int id = rep * 256 + tid;              // 0..511 chunks of 16B
        int t = id >> 8, c = (id >> 2) & 63, s = id & 3;
        int sg = s ^ ((c >> 1) & 3);
        int jl = t * 32 + sg * 8;
        short* p = Ab + (size_t)t * 2048 + c * 32 + s * 8;
        uint4 v = *(uint4*)p;
        short* sp = (short*)&v;
        short o[8];
        #pragma unroll
        for (int e = 0; e < 8; ++e) o[e] = f2bf(bf2f(sp[e]) * Larr[jl + e]);
        *(uint4*)p = *(uint4*)o;
    }
}

// ------------------------------------------------------------------- k_attn
// Round-20: block = (br, mt of 128 m); 512 thr = 8 waves =
// (wj path) x (jsw j-half) x (mh m-half).  Per-wave register footprint is
// IDENTICAL to the round-14 4-wave kernel (2 m-subs, 4 accs, mf[2][4]);
// the extra m-coverage comes from waves, not registers -> no spill.
// Staged bytes per block unchanged (2 MB) but blocks halve (256) ->
// total staged 512 MB (was 1 GB).  Grid 256 = 1 block/CU, 8 waves/CU.
// Staging role: wave w stages tensor (w&3), j-half (w>>2): 4 KB/round.
__global__ __launch_bounds__(512, 2) void k_attn(char* __restrict__ ws)
{
    const int tid  = threadIdx.x;
    const int br   = blockIdx.x & 7;
    const int mt   = blockIdx.x >> 3;          // 0..31, m-tile of 128
    const int lane = tid & 63;
    const int w    = tid >> 6;                 // 0..7
    const int wj   = w & 1;                    // path: 0 = G1*A', 1 = G2*B
    const int jsw  = (w >> 1) & 1;             // j-half this wave computes
    const int mh   = w >> 2;                   // m-half (64 rows) this wave owns
    const int col  = lane & 31;
    const int l5   = lane >> 5;
    const bool hi  = (l5 != 0);

    const char* Qbb = ws + QP_OFF  + (size_t)br * REG_ELEMS * 2;
    const char* Kbb = ws + KP_OFF  + (size_t)br * REG_ELEMS * 2;
    const char* Abb = ws + ATL_OFF + (size_t)br * REG_ELEMS * 2;
    const char* Bbb = ws + BTL_OFF + (size_t)br * REG_ELEMS * 2;
    const float* Lnv = (const float*)(ws + LNV_OFF) + (size_t)br * 4096;
    short* OutPb    = (short*)(ws + OUTP_OFF) + (size_t)br * REG_ELEMS;

    __shared__ __align__(16) char smem[65536];  // dbuf 2 x (2 js x 16K); red overlay

    // both m-fragment sets (m-sub 0 and 1) within this wave's m-half
    const short* msrcb = (const short*)(wj == 0 ? Kbb : Qbb);
    bf16x8 mf[2][4];
    #pragma unroll
    for (int h = 0; h < 2; ++h) {
        const short* mr = msrcb + (size_t)(mt * 128 + mh * 64 + h * 32 + col) * 64;
        #pragma unroll
        for (int s = 0; s < 4; ++s)
            mf[h][s] = *(const bf16x8*)(mr + ((2*s+l5) ^ (col & 7)) * 8);
    }

    f32x16 acc00 = zero16(), acc01 = zero16();  // m-sub0: cols 0-31 / 32-63
    f32x16 acc10 = zero16(), acc11 = zero16();  // m-sub1

    // staging role: wave w stages tensor (w&3) for j-half (w>>2)
    // (4 KB = 4 stage16 per round per wave; 8 waves cover the 32 KB slab)
    const int tt = w & 3;
    const int hh = w >> 2;
    const char* gsb = (tt == 0) ? Qbb : (tt == 1) ? Kbb : (tt == 2) ? Abb : Bbb;

    {   // stage round 0
        const char* g = gsb + (size_t)hh * 262144 + lane * 16;
        char* l = smem + hh * 16384 + tt * 4096 + lane * 16;
        #pragma unroll
        for (int i = 0; i < 4; ++i) stage16(g + i * 1024, l + i * 1024);
    }

    #pragma unroll 2
    for (int rnd = 0; rnd < 64; ++rnd) {
        __syncthreads();
        if (rnd + 1 < 64) {
            const char* g = gsb + (size_t)hh * 262144
                            + (size_t)(rnd + 1) * 4096 + lane * 16;
            char* l = smem + ((rnd + 1) & 1) * 32768 + hh * 16384
                      + tt * 4096 + lane * 16;
            #pragma unroll
            for (int i = 0; i < 4; ++i) stage16(g + i * 1024, l + i * 1024);
        }
        const char* sb = smem + (rnd & 1) * 32768 + jsw * 16384;
        const short* jr = (const short*)(sb + (wj == 0 ? 0 : 4096));      // Q | K rows
        const short* ts = (const short*)(sb + (wj == 0 ? 8192 : 12288));  // A' | B tile

        // one set of jr reads serves both m-halves
        bf16x8 a[4];
        #pragma unroll
        for (int s = 0; s < 4; ++s)
            a[s] = *(const bf16x8*)(jr + col * 64 + ((2*s+l5) ^ (col & 7)) * 8);

        f32x16 d0 = zero16(), d1 = zero16();
        #pragma unroll
        for (int s = 0; s < 4; ++s) {
            d0 = MFMA32(a[s], mf[0][s], d0);
            d1 = MFMA32(a[s], mf[1][s], d1);
        }

        // raw exp2 weights (normalizers folded in A' / deferred via Linv[m])
        unsigned W0[8], W1[8];
        #pragma unroll
        for (int q = 0; q < 4; ++q) {
            W0[2*q]   = pack_trunc(fexp2(d0[4*q]),   fexp2(d0[4*q+1]));
            W0[2*q+1] = pack_trunc(fexp2(d0[4*q+2]), fexp2(d0[4*q+3]));
            W1[2*q]   = pack_trunc(fexp2(d1[4*q]),   fexp2(d1[4*q+1]));
            W1[2*q+1] = pack_trunc(fexp2(d1[4*q+2]), fexp2(d1[4*q+3]));
        }

        // transpose both weight sets; shared ts reads feed 4 out-MFMAs
        #pragma unroll
        for (int k16 = 0; k16 < 2; ++k16) {
            unsigned u0 = W0[4*k16+0], u1 = W0[4*k16+1];
            unsigned u2 = W0[4*k16+2], u3 = W0[4*k16+3];
            permswap32(u0, u2, hi);
            permswap32(u1, u3, hi);
            union { uint4 u; bf16x8 v; } fr0;
            fr0.u.x = u0; fr0.u.y = u1; fr0.u.z = u2; fr0.u.w = u3;

            unsigned v0 = W1[4*k16+0], v1 = W1[4*k16+1];
            unsigned v2 = W1[4*k16+2], v3 = W1[4*k16+3];
            permswap32(v0, v2, hi);
            permswap32(v1, v3, hi);
            union { uint4 u; bf16x8 v; } fr1;
            fr1.u.x = v0; fr1.u.y = v1; fr1.u.z = v2; fr1.u.w = v3;

            const int swz = ((2*k16 + l5) ^ ((col >> 1) & 3)) * 8;
            bf16x8 bL = *(const bf16x8*)(ts + col * 32 + swz);
            bf16x8 bH = *(const bf16x8*)(ts + (col + 32) * 32 + swz);
            acc00 = MFMA32(fr0.v, bL, acc00);
            acc01 = MFMA32(fr0.v, bH, acc01);
            acc10 = MFMA32(fr1.v, bL, acc10);
            acc11 = MFMA32(fr1.v, bH, acc11);
        }
    }

    // epilogue: f32 combine across the 4 (wj,jsw) roles; the two m-halves
    // write disjoint red rows so they share each phase.
    // red = [128][68] f32 = 34816 B (fits the 64 KB smem overlay).
    __syncthreads();
    float* red = (float*)smem;
    const int low2 = w & 3;                    // (jsw<<1) | wj role id
    if (low2 == 0) {                           // wj=0, jsw=0 : write
        #pragma unroll
        for (int h = 0; h < 2; ++h)
            #pragma unroll
            for (int r = 0; r < 16; ++r) {
                int ml = mh * 64 + h * 32 + (r & 3) + 8 * (r >> 2) + 4 * l5;
                red[ml * 68 + col]      = h ? acc10[r] : acc00[r];
                red[ml * 68 + 32 + col] = h ? acc11[r] : acc01[r];
            }
    }
    __syncthreads();
    if (low2 == 2) {                           // wj=0, jsw=1 : add
        #pragma unroll
        for (int h = 0; h < 2; ++h)
            #pragma unroll
            for (int r = 0; r < 16; ++r) {
                int ml = mh * 64 + h * 32 + (r & 3) + 8 * (r >> 2) + 4 * l5;
                red[ml * 68 + col]      += h ? acc10[r] : acc00[r];
                red[ml * 68 + 32 + col] += h ? acc11[r] : acc01[r];
            }
    }
    __syncthreads();
    if (low2 == 1) {                           // wj=1, jsw=0 : add * Linv[m]
        #pragma unroll
        for (int h = 0; h < 2; ++h)
            #pragma unroll
            for (int r = 0; r < 16; ++r) {
                int ml = mh * 64 + h * 32 + (r & 3) + 8 * (r >> 2) + 4 * l5;
                float li = Lnv[mt * 128 + ml];
                red[ml * 68 + col]      += li * (h ? acc10[r] : acc00[r]);
                red[ml * 68 + 32 + col] += li * (h ? acc11[r] : acc01[r]);
            }
    }
    __syncthreads();
    if (low2 == 3) {                           // wj=1, jsw=1 : add * Linv[m]
        #pragma unroll
        for (int h = 0; h < 2; ++h)
            #pragma unroll
            for (int r = 0; r < 16; ++r) {
                int ml = mh * 64 + h * 32 + (r & 3) + 8 * (r >> 2) + 4 * l5;
                float li = Lnv[mt * 128 + ml];
                red[ml * 68 + col]      += li * (h ? acc10[r] : acc00[r]);
                red[ml * 68 + 32 + col] += li * (h ? acc11[r] : acc01[r]);
            }
    }
    __syncthreads();
    {
        const int m  = tid >> 2;               // 0..127
        const int c0 = (tid & 3) * 16;
        const float* rp = red + m * 68 + c0;
        uint4 p0, p1;
        p0.x = pack_trunc(rp[0],  rp[1]);  p0.y = pack_trunc(rp[2],  rp[3]);
        p0.z = pack_trunc(rp[4],  rp[5]);  p0.w = pack_trunc(rp[6],  rp[7]);
        p1.x = pack_trunc(rp[8],  rp[9]);  p1.y = pack_trunc(rp[10], rp[11]);
        p1.z = pack_trunc(rp[12], rp[13]); p1.w = pack_trunc(rp[14], rp[15]);
        short* orow = OutPb + (size_t)(mt * 128 + m) * 64 + c0;
        *(uint4*)orow       = p0;
        *(uint4*)(orow + 8) = p1;
    }
}

// --------------------------------------------------------------- k_conv_out
// (r13 green verbatim: 256-thread remap, single OutP)
__global__ __launch_bounds__(256) void k_conv_out(
    const char* __restrict__ ws,
    const float* __restrict__ Wo, const float* __restrict__ bo,
    float* __restrict__ out)
{
    const int tid  = threadIdx.x;
    const int lane = tid & 63;
    const int sub  = tid >> 6;                 // 0..3
    const int blk  = blockIdx.x;               // 0..255
    const int br   = blk & 7;
    const int nt   = (blk >> 3) * 4 + sub;     // 0..127
    const int col  = lane & 31;
    const int l5   = lane >> 5;

    const short* OutPb = (const short*)(ws + OUTP_OFF) + (size_t)br * REG_ELEMS;

    bf16x8 afr[4];
    const short* arow = OutPb + (size_t)(nt * 32 + col) * 64 + l5 * 8;
    #pragma unroll
    for (int s = 0; s < 4; ++s) afr[s] = *(const bf16x8*)(arow + s * 16);

    bf16x8 bw[2][4];
    #pragma unroll
    for (int oh = 0; oh < 2; ++oh) {
        const float* wrow = Wo + (size_t)(oh * 32 + col) * 64 + l5 * 8;
        #pragma unroll
        for (int s = 0; s < 4; ++s) {
            float4 f0 = *(const float4*)(wrow + s * 16);
            float4 f1 = *(const float4*)(wrow + s * 16 + 4);
            union { bf16x8 v; short sh[8]; } u;
            u.sh[0] = f2bf(f0.x); u.sh[1] = f2bf(f0.y);
            u.sh[2] = f2bf(f0.z); u.sh[3] = f2bf(f0.w);
            u.sh[4] = f2bf(f1.x); u.sh[5] = f2bf(f1.y);
            u.sh[6] = f2bf(f1.z); u.sh[7] = f2bf(f1.w);
            bw[oh][s] = u.v;
        }
    }

    f32x16 d0 = zero16(), d1 = zero16();
    #pragma unroll
    for (int s = 0; s < 4; ++s) {
        d0 = MFMA32(afr[s], bw[0][s], d0);
        d1 = MFMA32(afr[s], bw[1][s], d1);
    }

    const int b  = br >> 2;
    const int gi = (br >> 1) & 1;
    const int gj = br & 1;

    #pragma unroll
    for (int oh = 0; oh < 2; ++oh) {
        const int oc = oh * 32 + col;
        const float bias = bo[oc];
        const f32x16& d = oh ? d1 : d0;
        #pragma unroll
        for (int q = 0; q < 4; ++q) {
            int nloc = 8 * q + 4 * l5;
            int nreg = nt * 32 + nloc;
            int wp   = nreg & 63;
            int ip   = nreg >> 6;
            float4 v = make_float4(d[4*q+0] + bias, d[4*q+1] + bias,
                                   d[4*q+2] + bias, d[4*q+3] + bias);
            float* op = out + ((size_t)(b * 64 + oc)) * 16384
                        + (size_t)(gi * 64 + ip) * 128 + gj * 64 + wp;
            *(float4*)op = v;
        }
    }
}

// -------------------------------------------------------------------- launch
extern "C" void kernel_launch(void* const* d_in, const int* in_sizes, int n_in,
                              void* d_out, int out_size, void* d_ws, size_t ws_size,
                              hipStream_t stream)
{
    const float* x  = (const float*)d_in[0];
    const float* Wq = (const float*)d_in[1];
    const float* bq = (const float*)d_in[2];
    const float* Wk = (const float*)d_in[3];
    const float* bk = (const float*)d_in[4];
    const float* Wa = (const float*)d_in[5];
    const float* ba = (const float*)d_in[6];
    const float* Wb = (const float*)d_in[7];
    const float* bb = (const float*)d_in[8];
    const float* Wo = (const float*)d_in[9];
    const float* bo = (const float*)d_in[10];
    char* ws   = (char*)d_ws;
    float* out = (float*)d_out;

    hipLaunchKernelGGL(k_conv_in,  dim3(512),  dim3(256), 0, stream,
                       x, Wq, bq, Wk, bk, Wa, ba, Wb, bb, ws);
    hipLaunchKernelGGL(k_stats,    dim3(1024), dim3(256), 0, stream, ws);
    hipLaunchKernelGGL(k_ascale,   dim3(512),  dim3(256), 0, stream, ws);
    hipLaunchKernelGGL(k_attn,     dim3(256),  dim3(512), 0, stream, ws);
    hipLaunchKernelGGL(k_conv_out, dim3(256),  dim3(256), 0, stream,
                       ws, Wo, bo, out);
}

// Round 2
// 194.057 us; speedup vs baseline: 1.0531x; 1.0198x over previous
//
#include <hip/hip_runtime.h>

// RegionSeparatedAttention on MI355X — round 21: k_attn cross-round ILP via
// triple-buffered single-barrier rounds.
//
// Post-mortem r20: halving staged bytes (1GB->512MB) only gave 88->80 us ->
// staging BW was NOT the binder.  Per-round cost ~2600 cyc vs resource tally
// (MFMA 256, VALU ~800 incl 512 cyc exp2, LDS ~1000) -> serialization: the
// per-wave chain (ds_read -> d-MFMA -> exp2 -> perm -> out-MFMA) is strictly
// serial and the per-round barrier keeps all waves in phase, so pipes never
// overlap.  Fix: 3 LDS slabs; each round reads slab r (ts) AND slab r+1 (jr)
// in one barrier-free region while stage lands in slab r+2.  d(r+1) QK-MFMAs
// are independent of exp2(d(r)) and out-MFMA(r) -> scheduler overlaps MFMA /
// trans / LDS pipes within each wave.
//
// Global layouts in ws (per region br = b*4 + gi*2 + gj), ALL pre-swizzled:
//   Qp,Kp : bf16 [8][4096 n][64 c] pixel-major rows, seg' = seg ^ (n & 7)
//           (Q pre-scaled by 0.125*log2e)
//   Atl,Btl: bf16 [8][128 jtile][64 c][32 j], seg' = seg ^ ((c>>1) & 3)
//           (A gets *= Linv[j] in k_ascale)
//   OutP  : bf16 [8][4096 n][64 c] pixel-major, UNswizzled
//   Linv  : f32 [8][4096]   (1 / softmax row sum, from k_ascale)
//   Lpart : f32 [2 ms][8][4096] partial row sums (k_stats)

typedef __attribute__((ext_vector_type(8)))  short bf16x8;
typedef __attribute__((ext_vector_type(16))) float f32x16;

#define MFMA32(a, b, c) __builtin_amdgcn_mfma_f32_32x32x16_bf16(a, b, c, 0, 0, 0)

constexpr int REG_ELEMS = 4096 * 64;
constexpr size_t QP_OFF    = 0;
constexpr size_t KP_OFF    = 4u  << 20;
constexpr size_t ATL_OFF   = 8u  << 20;
constexpr size_t BTL_OFF   = 12u << 20;
constexpr size_t OUTP_OFF  = 16u << 20;
constexpr size_t LNV_OFF   = 20u << 20;                  // f32 [8][4096]
constexpr size_t LPART_OFF = (20u << 20) + (128u << 10); // f32 [2][8][4096]

constexpr float QSCALE = 0.18033688011112042f;  // 0.125 * log2(e)

__device__ __forceinline__ short f2bf(float f) {   // RNE
    union { float f; unsigned u; } v; v.f = f;
    unsigned r = v.u + 0x7fffu + ((v.u >> 16) & 1u);
    return (short)(r >> 16);
}
__device__ __forceinline__ float bf2f(short s) {
    union { unsigned u; float f; } v; v.u = ((unsigned)(unsigned short)s) << 16;
    return v.f;
}
__device__ __forceinline__ unsigned fbits(float f) {
    union { float f; unsigned u; } v; v.f = f; return v.u;
}
__device__ __forceinline__ unsigned pack_trunc(float e0, float e1) {
    return __builtin_amdgcn_perm(fbits(e1), fbits(e0), 0x07060302u);
}
__device__ __forceinline__ f32x16 zero16() {
    f32x16 z;
    #pragma unroll
    for (int i = 0; i < 16; ++i) z[i] = 0.f;
    return z;
}
__device__ __forceinline__ float fexp2(float x) {
#if __has_builtin(__builtin_amdgcn_exp2f)
    return __builtin_amdgcn_exp2f(x);
#else
    return exp2f(x);
#endif
}
__device__ __forceinline__ void permswap32(unsigned& a, unsigned& b, bool hi) {
#if __has_builtin(__builtin_amdgcn_permlane32_swap)
    auto r = __builtin_amdgcn_permlane32_swap(a, b, false, false);
    a = r[0]; b = r[1];
#elif __has_builtin(__builtin_amdgcn_permlane32_swap_b32)
    auto r = __builtin_amdgcn_permlane32_swap_b32(a, b, false, false);
    a = r[0]; b = r[1];
#else
    unsigned ax = (unsigned)__shfl_xor((int)a, 32);
    unsigned bx = (unsigned)__shfl_xor((int)b, 32);
    unsigned na = hi ? bx : a;
    unsigned nb = hi ? b  : ax;
    a = na; b = nb;
#endif
}

typedef __attribute__((address_space(1))) const unsigned char as1_t;
typedef __attribute__((address_space(3))) unsigned char as3_t;
__device__ __forceinline__ void stage16(const void* g, void* l) {
    __builtin_amdgcn_global_load_lds((as1_t*)g, (as3_t*)l, 16, 0, 0);
}

// ---------------------------------------------------------------- k_conv_in
// (round-8/13 green verbatim)
__global__ __launch_bounds__(256) void k_conv_in(
    const float* __restrict__ x,
    const float* __restrict__ Wq, const float* __restrict__ bq,
    const float* __restrict__ Wk, const float* __restrict__ bk,
    const float* __restrict__ Wa, const float* __restrict__ ba,
    const float* __restrict__ Wb, const float* __restrict__ bb,
    char* __restrict__ ws)
{
    const int tid  = threadIdx.x;
    const int blk  = blockIdx.x;
    const int wseg = blk & 1;
    const int h    = (blk >> 1) & 127;
    const int b    = blk >> 8;
    const int br   = b * 4 + (h >> 6) * 2 + wseg;
    const int n0   = (h & 63) * 64;

    __shared__ float xs[64][68];               // [c][px]
    __shared__ short trans[2][64][72];         // [mat][px][oc]

    const float* xp = x + ((size_t)b * 64 * 16384) + (size_t)h * 128 + wseg * 64;
    #pragma unroll
    for (int r = 0; r < 4; ++r) {
        int idx = r * 256 + tid;
        int c   = idx >> 4;
        int w4  = (idx & 15) << 2;
        *(float4*)&xs[c][w4] = *(const float4*)(xp + (size_t)c * 16384 + w4);
    }
    __syncthreads();

    const int lane = tid & 63;
    const int wid  = tid >> 6;
    const int col  = lane & 31;
    const int l5   = lane >> 5;
    const int pH   = wid & 1;                  // pixel half
    const int oH   = wid >> 1;                 // oc half
    const int px   = pH * 32 + col;
    const int oc   = oH * 32 + col;

    bf16x8 xhi[4], xlo[4];
    #pragma unroll
    for (int s = 0; s < 4; ++s) {
        union { bf16x8 v; short sh[8]; } uh, ul;
        #pragma unroll
        for (int e = 0; e < 8; ++e) {
            float xv = xs[s * 16 + l5 * 8 + e][px];
            short hh = f2bf(xv);
            uh.sh[e] = hh;
            ul.sh[e] = f2bf(xv - bf2f(hh));
        }
        xhi[s] = uh.v; xlo[s] = ul.v;
    }

    #pragma unroll
    for (int mat = 0; mat < 4; ++mat) {
        const float* Wsel = (mat == 0) ? Wq : (mat == 1) ? Wk : (mat == 2) ? Wa : Wb;
        const float* bsel = (mat == 0) ? bq : (mat == 1) ? bk : (mat == 2) ? ba : bb;

        bf16x8 whi[4], wlo[4];
        const float* wrow = Wsel + (size_t)oc * 64;
        #pragma unroll
        for (int s = 0; s < 4; ++s) {
            float4 f0 = *(const float4*)(wrow + s * 16 + l5 * 8);
            float4 f1 = *(const float4*)(wrow + s * 16 + l5 * 8 + 4);
            float wf[8] = { f0.x, f0.y, f0.z, f0.w, f1.x, f1.y, f1.z, f1.w };
            union { bf16x8 v; short sh[8]; } uh, ul;
            #pragma unroll
            for (int e = 0; e < 8; ++e) {
                short hh = f2bf(wf[e]);
                uh.sh[e] = hh;
                ul.sh[e] = f2bf(wf[e] - bf2f(hh));
            }
            whi[s] = uh.v; wlo[s] = ul.v;
        }

        f32x16 d = zero16();
        #pragma unroll
        for (int s = 0; s < 4; ++s) {
            d = MFMA32(xhi[s], whi[s], d);
            d = MFMA32(xhi[s], wlo[s], d);
            d = MFMA32(xlo[s], whi[s], d);
        }

        const float bias = bsel[oc];
        if (mat < 2) {
            const float sc = (mat == 0) ? QSCALE : 1.0f;
            #pragma unroll
            for (int r = 0; r < 16; ++r) {
                int pxl = pH * 32 + (r & 3) + 8 * (r >> 2) + 4 * l5;
                trans[mat][pxl][oc] = f2bf((d[r] + bias) * sc);
            }
        } else {
            short* base = (short*)(ws + (mat == 2 ? ATL_OFF : BTL_OFF))
                          + (size_t)br * REG_ELEMS;
            const int sw   = (oc >> 1) & 3;
            const int tile = (n0 >> 5) + pH;
            #pragma unroll
            for (int q = 0; q < 4; ++q) {
                short tmp4[4];
                #pragma unroll
                for (int rr = 0; rr < 4; ++rr) tmp4[rr] = f2bf(d[4 * q + rr] + bias);
                int segp = q ^ sw;
                short* p = base + (size_t)tile * 2048 + oc * 32 + segp * 8 + 4 * l5;
                *(uint2*)p = *(uint2*)tmp4;
            }
        }
    }
    __syncthreads();

    #pragma unroll
    for (int rep = 0; rep < 4; ++rep) {
        int idx  = rep * 256 + tid;
        int mat2 = idx >> 9;
        int row  = (idx >> 3) & 63;
        int seg  = idx & 7;
        short* dst = (short*)(ws + (mat2 ? KP_OFF : QP_OFF))
                     + (size_t)br * REG_ELEMS + (size_t)(n0 + row) * 64
                     + (seg ^ (row & 7)) * 8;
        *(uint4*)dst = *(uint4*)&trans[mat2][row][seg * 8];
    }
}

// ------------------------------------------------------------------ k_stats
// (r13 green m-split verbatim)
__global__ __launch_bounds__(256, 2) void k_stats(char* __restrict__ ws)
{
    const int tid  = threadIdx.x;
    const int br   = blockIdx.x & 7;
    const int nt   = (blockIdx.x >> 3) & 63;
    const int ms   = blockIdx.x >> 9;          // m-half
    const int lane = tid & 63;
    const int w    = tid >> 6;
    const int wn   = w & 1;
    const int wi   = w >> 1;
    const int col  = lane & 31;
    const int l5   = lane >> 5;

    const short* Qb  = (const short*)(ws + QP_OFF) + (size_t)br * REG_ELEMS;
    const char*  Kbb = ws + KP_OFF + (size_t)br * REG_ELEMS * 2
                       + (size_t)ms * 262144;  // 2048 rows * 128 B

    __shared__ __align__(16) char smem[16896];  // dbuf 16K | Lred 512

    const int nrow = nt * 64 + wn * 32 + col;
    bf16x8 afr[4];
    #pragma unroll
    for (int s = 0; s < 4; ++s)
        afr[s] = *(const bf16x8*)(Qb + (size_t)nrow * 64 + (((2*s+l5) ^ (col & 7)) * 8));

    float sm[16];
    #pragma unroll
    for (int r = 0; r < 16; ++r) sm[r] = 0.f;

    {   // stage slab 0 (64 m-rows = 8 KB; wave w covers 2 KB)
        const char* g = Kbb + (size_t)w * 2048 + lane * 16;
        char* l = smem + w * 2048;
        stage16(g, l); stage16(g + 1024, l + 1024);
    }

    #pragma unroll 2
    for (int slab = 0; slab < 32; ++slab) {
        __syncthreads();
        if (slab + 1 < 32) {
            const char* g = Kbb + (size_t)(slab + 1) * 8192 + w * 2048 + lane * 16;
            char* l = smem + ((slab + 1) & 1) * 8192 + w * 2048;
            stage16(g, l); stage16(g + 1024, l + 1024);
        }
        const short* Ks = (const short*)(smem + (slab & 1) * 8192);
        f32x16 d = zero16();
        #pragma unroll
        for (int s = 0; s < 4; ++s) {
            bf16x8 bf = *(const bf16x8*)(Ks + (wi * 32 + col) * 64
                                         + ((2*s+l5) ^ (col & 7)) * 8);
            d = MFMA32(afr[s], bf, d);
        }
        #pragma unroll
        for (int r = 0; r < 16; ++r) sm[r] += fexp2(d[r]);
    }

    #pragma unroll
    for (int off = 1; off < 32; off <<= 1)
        #pragma unroll
        for (int r = 0; r < 16; ++r) sm[r] += __shfl_xor(sm[r], off);

    __syncthreads();
    float* Lred = (float*)(smem + 16384);      // [4][32]
    if (col == 0) {
        #pragma unroll
        for (int r = 0; r < 16; ++r)
            Lred[w * 32 + ((r & 3) + 8 * (r >> 2) + 4 * l5)] = sm[r];
    }
    __syncthreads();
    if (tid < 64) {
        int wn2 = tid >> 5, nl = tid & 31;
        float L = Lred[wn2 * 32 + nl] + Lred[(wn2 + 2) * 32 + nl];
        ((float*)(ws + LPART_OFF))[(size_t)ms * 32768 + (size_t)br * 4096
                                   + nt * 64 + tid] = L;
    }
}

// ------------------------------------------------------------------ k_ascale
// (r13 green verbatim)
__global__ __launch_bounds__(256) void k_ascale(char* __restrict__ ws)
{
    const int tid = threadIdx.x;
    const int br  = blockIdx.x & 7;
    const int nt  = blockIdx.x >> 3;           // 0..63

    __shared__ float Larr[64];

    if (tid < 64) {
        const float* Lp = (const float*)(ws + LPART_OFF);
        const size_t idx = (size_t)br * 4096 + nt * 64 + tid;
        float li = 1.0f / (Lp[idx] + Lp[32768 + idx]);
        Larr[tid] = li;
        ((float*)(ws + LNV_OFF))[idx] = li;
    }
    __syncthreads();

    short* Ab = (short*)(ws + ATL_OFF) + (size_t)br * REG_ELEMS + (size_t)nt * 4096;
    #pragma unroll
    for (int rep = 0; rep < 2; ++rep) {
        int id = rep * 256 + tid;              // 0..511 chunks of 16B
        int t = id >> 8, c = (id >> 2) & 63, s = id & 3;
        int sg = s ^ ((c >> 1) & 3);
        int jl = t * 32 + sg * 8;
        short* p = Ab + (size_t)t * 2048 + c * 32 + s * 8;
        uint4 v = *(uint4*)p;
        short* sp = (short*)&v;
        short o[8];
        #pragma unroll
        for (int e = 0; e < 8; ++e) o[e] = f2bf(bf2f(sp[e]) * Larr[jl + e]);
        *(uint4*)p = *(uint4*)o;
    }
}

// ------------------------------------------------------------------- k_attn
// Round-21: block = (br, mt of 128 m); 512 thr = 8 waves =
// (wj path) x (jsw j-half) x (mh m-half).  TRIPLE-buffered slabs (3 x 32 KB);
// one vmcnt(0)+s_barrier per round; each round's barrier-free region holds:
//   stage(r+2) issue | jr(r+1) ds_reads + d(r+1) QK-MFMAs | exp2/pack/perm
//   of d(r) | ts(r) ds_reads + out-MFMA(r)
// The d(r+1) chain and out-MFMA(r) are independent of the exp2(d(r)) chain,
// so MFMA / transcendental / LDS pipes overlap WITHIN each wave instead of
// relying on cross-wave skew (which the barrier kills).
__global__ __launch_bounds__(512, 2) void k_attn(char* __restrict__ ws)
{
    const int tid  = threadIdx.x;
    const int br   = blockIdx.x & 7;
    const int mt   = blockIdx.x >> 3;          // 0..31, m-tile of 128
    const int lane = tid & 63;
    const int w    = tid >> 6;                 // 0..7
    const int wj   = w & 1;                    // path: 0 = G1*A', 1 = G2*B
    const int jsw  = (w >> 1) & 1;             // j-half this wave computes
    const int mh   = w >> 2;                   // m-half (64 rows) this wave owns
    const int col  = lane & 31;
    const int l5   = lane >> 5;
    const bool hi  = (l5 != 0);

    const char* Qbb = ws + QP_OFF  + (size_t)br * REG_ELEMS * 2;
    const char* Kbb = ws + KP_OFF  + (size_t)br * REG_ELEMS * 2;
    const char* Abb = ws + ATL_OFF + (size_t)br * REG_ELEMS * 2;
    const char* Bbb = ws + BTL_OFF + (size_t)br * REG_ELEMS * 2;
    const float* Lnv = (const float*)(ws + LNV_OFF) + (size_t)br * 4096;
    short* OutPb    = (short*)(ws + OUTP_OFF) + (size_t)br * REG_ELEMS;

    __shared__ __align__(16) char smem[98304];  // 3 slabs x 32 KB; red overlay

    // both m-fragment sets (m-sub 0 and 1) within this wave's m-half
    const short* msrcb = (const short*)(wj == 0 ? Kbb : Qbb);
    bf16x8 mf[2][4];
    #pragma unroll
    for (int h = 0; h < 2; ++h) {
        const short* mr = msrcb + (size_t)(mt * 128 + mh * 64 + h * 32 + col) * 64;
        #pragma unroll
        for (int s = 0; s < 4; ++s)
            mf[h][s] = *(const bf16x8*)(mr + ((2*s+l5) ^ (col & 7)) * 8);
    }

    // staging role: wave w stages tensor (w&3) for j-half (w>>2): 4 KB/round
    const int tt = w & 3;
    const int hh = w >> 2;
    const char* gsb = (tt == 0) ? Qbb : (tt == 1) ? Kbb : (tt == 2) ? Abb : Bbb;

    auto stageRound = [&](char* slab, int rnd) {
        const char* g = gsb + (size_t)hh * 262144 + (size_t)rnd * 4096 + lane * 16;
        char* l = slab + hh * 16384 + tt * 4096 + lane * 16;
        #pragma unroll
        for (int i = 0; i < 4; ++i) stage16(g + i * 1024, l + i * 1024);
    };

    char* sA = smem;              // slab holding round r   (ts source)
    char* sB = smem + 32768;      // slab holding round r+1 (jr source)
    char* sC = smem + 65536;      // slab being staged with round r+2

    stageRound(sA, 0);
    stageRound(sB, 1);

    const int jroff = jsw * 16384 + (wj == 0 ? 0 : 4096);
    const int tsoff = jsw * 16384 + (wj == 0 ? 8192 : 12288);

    // prologue: drain, sync, compute d(0) from slab A
    asm volatile("s_waitcnt vmcnt(0)\n\ts_barrier" ::: "memory");

    f32x16 d0, d1;
    {
        const short* jr = (const short*)(sA + jroff);
        bf16x8 a[4];
        #pragma unroll
        for (int s = 0; s < 4; ++s)
            a[s] = *(const bf16x8*)(jr + col * 64 + ((2*s+l5) ^ (col & 7)) * 8);
        d0 = zero16(); d1 = zero16();
        #pragma unroll
        for (int s = 0; s < 4; ++s) {
            d0 = MFMA32(a[s], mf[0][s], d0);
            d1 = MFMA32(a[s], mf[1][s], d1);
        }
    }

    f32x16 acc00 = zero16(), acc01 = zero16();  // m-sub0: cols 0-31 / 32-63
    f32x16 acc10 = zero16(), acc11 = zero16();  // m-sub1

    #pragma unroll 2
    for (int rnd = 0; rnd < 64; ++rnd) {
        // one drain+barrier per round: stage(r+1) landed for all waves
        // (issued a full round ago) + all reads of slab C's old contents done.
        asm volatile("s_waitcnt vmcnt(0)\n\ts_barrier" ::: "memory");
        if (rnd + 2 < 64) stageRound(sC, rnd + 2);

        // --- next-round QK chain (independent of exp2/out below) ---
        f32x16 n0, n1;
        if (rnd + 1 < 64) {
            const short* jr = (const short*)(sB + jroff);
            bf16x8 a[4];
            #pragma unroll
            for (int s = 0; s < 4; ++s)
                a[s] = *(const bf16x8*)(jr + col * 64 + ((2*s+l5) ^ (col & 7)) * 8);
            n0 = zero16(); n1 = zero16();
            #pragma unroll
            for (int s = 0; s < 4; ++s) {
                n0 = MFMA32(a[s], mf[0][s], n0);
                n1 = MFMA32(a[s], mf[1][s], n1);
            }
        }

        // --- exp2 weights of round r (VALU/trans pipe) ---
        unsigned W0[8], W1[8];
        #pragma unroll
        for (int q = 0; q < 4; ++q) {
            W0[2*q]   = pack_trunc(fexp2(d0[4*q]),   fexp2(d0[4*q+1]));
            W0[2*q+1] = pack_trunc(fexp2(d0[4*q+2]), fexp2(d0[4*q+3]));
            W1[2*q]   = pack_trunc(fexp2(d1[4*q]),   fexp2(d1[4*q+1]));
            W1[2*q+1] = pack_trunc(fexp2(d1[4*q+2]), fexp2(d1[4*q+3]));
        }

        // --- transpose + out-MFMAs of round r (ts from slab A) ---
        const short* ts = (const short*)(sA + tsoff);
        #pragma unroll
        for (int k16 = 0; k16 < 2; ++k16) {
            unsigned u0 = W0[4*k16+0], u1 = W0[4*k16+1];
            unsigned u2 = W0[4*k16+2], u3 = W0[4*k16+3];
            permswap32(u0, u2, hi);
            permswap32(u1, u3, hi);
            union { uint4 u; bf16x8 v; } fr0;
            fr0.u.x = u0; fr0.u.y = u1; fr0.u.z = u2; fr0.u.w = u3;

            unsigned v0 = W1[4*k16+0], v1 = W1[4*k16+1];
            unsigned v2 = W1[4*k16+2], v3 = W1[4*k16+3];
            permswap32(v0, v2, hi);
            permswap32(v1, v3, hi);
            union { uint4 u; bf16x8 v; } fr1;
            fr1.u.x = v0; fr1.u.y = v1; fr1.u.z = v2; fr1.u.w = v3;

            const int swz = ((2*k16 + l5) ^ ((col >> 1) & 3)) * 8;
            bf16x8 bL = *(const bf16x8*)(ts + col * 32 + swz);
            bf16x8 bH = *(const bf16x8*)(ts + (col + 32) * 32 + swz);
            acc00 = MFMA32(fr0.v, bL, acc00);
            acc01 = MFMA32(fr0.v, bH, acc01);
            acc10 = MFMA32(fr1.v, bL, acc10);
            acc11 = MFMA32(fr1.v, bH, acc11);
        }

        if (rnd + 1 < 64) { d0 = n0; d1 = n1; }
        char* t = sA; sA = sB; sB = sC; sC = t;
    }

    // epilogue: f32 combine across the 4 (wj,jsw) roles; the two m-halves
    // write disjoint red rows so they share each phase.
    // red = [128][68] f32 = 34816 B (fits the 96 KB smem overlay).
    __syncthreads();
    float* red = (float*)smem;
    const int low2 = w & 3;                    // (jsw<<1) | wj role id
    if (low2 == 0) {                           // wj=0, jsw=0 : write
        #pragma unroll
        for (int h = 0; h < 2; ++h)
            #pragma unroll
            for (int r = 0; r < 16; ++r) {
                int ml = mh * 64 + h * 32 + (r & 3) + 8 * (r >> 2) + 4 * l5;
                red[ml * 68 + col]      = h ? acc10[r] : acc00[r];
                red[ml * 68 + 32 + col] = h ? acc11[r] : acc01[r];
            }
    }
    __syncthreads();
    if (low2 == 2) {                           // wj=0, jsw=1 : add
        #pragma unroll
        for (int h = 0; h < 2; ++h)
            #pragma unroll
            for (int r = 0; r < 16; ++r) {
                int ml = mh * 64 + h * 32 + (r & 3) + 8 * (r >> 2) + 4 * l5;
                red[ml * 68 + col]      += h ? acc10[r] : acc00[r];
                red[ml * 68 + 32 + col] += h ? acc11[r] : acc01[r];
            }
    }
    __syncthreads();
    if (low2 == 1) {                           // wj=1, jsw=0 : add * Linv[m]
        #pragma unroll
        for (int h = 0; h < 2; ++h)
            #pragma unroll
            for (int r = 0; r < 16; ++r) {
                int ml = mh * 64 + h * 32 + (r & 3) + 8 * (r >> 2) + 4 * l5;
                float li = Lnv[mt * 128 + ml];
                red[ml * 68 + col]      += li * (h ? acc10[r] : acc00[r]);
                red[ml * 68 + 32 + col] += li * (h ? acc11[r] : acc01[r]);
            }
    }
    __syncthreads();
    if (low2 == 3) {                           // wj=1, jsw=1 : add * Linv[m]
        #pragma unroll
        for (int h = 0; h < 2; ++h)
            #pragma unroll
            for (int r = 0; r < 16; ++r) {
                int ml = mh * 64 + h * 32 + (r & 3) + 8 * (r >> 2) + 4 * l5;
                float li = Lnv[mt * 128 + ml];
                red[ml * 68 + col]      += li * (h ? acc10[r] : acc00[r]);
                red[ml * 68 + 32 + col] += li * (h ? acc11[r] : acc01[r]);
            }
    }
    __syncthreads();
    {
        const int m  = tid >> 2;               // 0..127
        const int c0 = (tid & 3) * 16;
        const float* rp = red + m * 68 + c0;
        uint4 p0, p1;
        p0.x = pack_trunc(rp[0],  rp[1]);  p0.y = pack_trunc(rp[2],  rp[3]);
        p0.z = pack_trunc(rp[4],  rp[5]);  p0.w = pack_trunc(rp[6],  rp[7]);
        p1.x = pack_trunc(rp[8],  rp[9]);  p1.y = pack_trunc(rp[10], rp[11]);
        p1.z = pack_trunc(rp[12], rp[13]); p1.w = pack_trunc(rp[14], rp[15]);
        short* orow = OutPb + (size_t)(mt * 128 + m) * 64 + c0;
        *(uint4*)orow       = p0;
        *(uint4*)(orow + 8) = p1;
    }
}

// --------------------------------------------------------------- k_conv_out
// (r13 green verbatim: 256-thread remap, single OutP)
__global__ __launch_bounds__(256) void k_conv_out(
    const char* __restrict__ ws,
    const float* __restrict__ Wo, const float* __restrict__ bo,
    float* __restrict__ out)
{
    const int tid  = threadIdx.x;
    const int lane = tid & 63;
    const int sub  = tid >> 6;                 // 0..3
    const int blk  = blockIdx.x;               // 0..255
    const int br   = blk & 7;
    const int nt   = (blk >> 3) * 4 + sub;     // 0..127
    const int col  = lane & 31;
    const int l5   = lane >> 5;

    const short* OutPb = (const short*)(ws + OUTP_OFF) + (size_t)br * REG_ELEMS;

    bf16x8 afr[4];
    const short* arow = OutPb + (size_t)(nt * 32 + col) * 64 + l5 * 8;
    #pragma unroll
    for (int s = 0; s < 4; ++s) afr[s] = *(const bf16x8*)(arow + s * 16);

    bf16x8 bw[2][4];
    #pragma unroll
    for (int oh = 0; oh < 2; ++oh) {
        const float* wrow = Wo + (size_t)(oh * 32 + col) * 64 + l5 * 8;
        #pragma unroll
        for (int s = 0; s < 4; ++s) {
            float4 f0 = *(const float4*)(wrow + s * 16);
            float4 f1 = *(const float4*)(wrow + s * 16 + 4);
            union { bf16x8 v; short sh[8]; } u;
            u.sh[0] = f2bf(f0.x); u.sh[1] = f2bf(f0.y);
            u.sh[2] = f2bf(f0.z); u.sh[3] = f2bf(f0.w);
            u.sh[4] = f2bf(f1.x); u.sh[5] = f2bf(f1.y);
            u.sh[6] = f2bf(f1.z); u.sh[7] = f2bf(f1.w);
            bw[oh][s] = u.v;
        }
    }

    f32x16 d0 = zero16(), d1 = zero16();
    #pragma unroll
    for (int s = 0; s < 4; ++s) {
        d0 = MFMA32(afr[s], bw[0][s], d0);
        d1 = MFMA32(afr[s], bw[1][s], d1);
    }

    const int b  = br >> 2;
    const int gi = (br >> 1) & 1;
    const int gj = br & 1;

    #pragma unroll
    for (int oh = 0; oh < 2; ++oh) {
        const int oc = oh * 32 + col;
        const float bias = bo[oc];
        const f32x16& d = oh ? d1 : d0;
        #pragma unroll
        for (int q = 0; q < 4; ++q) {
            int nloc = 8 * q + 4 * l5;
            int nreg = nt * 32 + nloc;
            int wp   = nreg & 63;
            int ip   = nreg >> 6;
            float4 v = make_float4(d[4*q+0] + bias, d[4*q+1] + bias,
                                   d[4*q+2] + bias, d[4*q+3] + bias);
            float* op = out + ((size_t)(b * 64 + oc)) * 16384
                        + (size_t)(gi * 64 + ip) * 128 + gj * 64 + wp;
            *(float4*)op = v;
        }
    }
}

// -------------------------------------------------------------------- launch
extern "C" void kernel_launch(void* const* d_in, const int* in_sizes, int n_in,
                              void* d_out, int out_size, void* d_ws, size_t ws_size,
                              hipStream_t stream)
{
    const float* x  = (const float*)d_in[0];
    const float* Wq = (const float*)d_in[1];
    const float* bq = (const float*)d_in[2];
    const float* Wk = (const float*)d_in[3];
    const float* bk = (const float*)d_in[4];
    const float* Wa = (const float*)d_in[5];
    const float* ba = (const float*)d_in[6];
    const float* Wb = (const float*)d_in[7];
    const float* bb = (const float*)d_in[8];
    const float* Wo = (const float*)d_in[9];
    const float* bo = (const float*)d_in[10];
    char* ws   = (char*)d_ws;
    float* out = (float*)d_out;

    hipLaunchKernelGGL(k_conv_in,  dim3(512),  dim3(256), 0, stream,
                       x, Wq, bq, Wk, bk, Wa, ba, Wb, bb, ws);
    hipLaunchKernelGGL(k_stats,    dim3(1024), dim3(256), 0, stream, ws);
    hipLaunchKernelGGL(k_ascale,   dim3(512),  dim3(256), 0, stream, ws);
    hipLaunchKernelGGL(k_attn,     dim3(256),  dim3(512), 0, stream, ws);
    hipLaunchKernelGGL(k_conv_out, dim3(256),  dim3(256), 0, stream,
                       ws, Wo, bo, out);
}